// Round 1
// baseline (579.575 us; speedup 1.0000x reference)
//
#include <hip/hip_runtime.h>
#include <hip/hip_bf16.h>
#include <math.h>

// Problem constants
constexpr int NB = 256;      // batch
constexpr int NL = 50;       // seq len
constexpr int ND = 128;      // dim
constexpr int NK = 4;        // interests
constexpr int NVm1 = 49999;  // V-1
constexpr int NPAD2 = 50176; // N padded to 392*128
constexpr int ROWS = NB * NL;   // 12800
constexpr int MROWS = NB * NK;  // 1024 (rows of select, b-major: row = b*4+k)
constexpr int GEMM_NSPAN = 512; // n cols per block in big GEMM (8 chunks of 64)
constexpr int MR = 64;          // rows per mega block

// prep kernel block ranges
constexpr int G_BN  = NPAD2 / 8;  // 6272 bnorm (8 rows/blk, float4 per thread)
constexpr int G_HS  = NB / 2;     // 128 hs (2 b/blk)
constexpr int G_PP  = NL / 2;     // 25 posPart (2 rows/blk)
constexpr int G_XB  = ROWS * ND / 2048; // 800 Xb cast
constexpr int G_W1T = ND * ND / 256;    // 64
constexpr int G_AWT = ND * ND / 256;    // 64
constexpr int G_GLT = ND * 512 / 256;   // 256
constexpr int G_TOT = G_BN + G_HS + G_PP + G_XB + G_W1T + G_AWT + G_GLT;

typedef __bf16 bf16x8 __attribute__((ext_vector_type(8)));
typedef float f32x4 __attribute__((ext_vector_type(4)));

__device__ __forceinline__ float sigm_fast(float x) { return 1.0f / (1.0f + __expf(-x)); }
__device__ __forceinline__ float sigm_prec(float x) { return 1.0f / (1.0f + expf(-x)); }
__device__ __forceinline__ float fast_tanh(float x) {
    float xc = fminf(fmaxf(x, -15.f), 15.f);
    float e = __expf(2.f * xc);
    return (e - 1.f) / (e + 1.f);
}

__device__ __forceinline__ void gld_lds16(const void* g, void* l) {
    __builtin_amdgcn_global_load_lds(
        (const __attribute__((address_space(1))) void*)g,
        (__attribute__((address_space(3))) void*)l, 16, 0, 0);
}

// ---------------- K0: prep — bnorm, hs, posPart, Xb cast, weight transposes ----------------
__global__ __launch_bounds__(256) void k_prep(
    const float* __restrict__ hidden, const int* __restrict__ mask,
    const float* __restrict__ pos_emb, const float* __restrict__ w1,
    const float* __restrict__ att_w2, const float* __restrict__ glu1_w,
    const float* __restrict__ emb,
    float* __restrict__ hs, float* __restrict__ posPart,
    __hip_bfloat16* __restrict__ XbG, __hip_bfloat16* __restrict__ w1h_t,
    __hip_bfloat16* __restrict__ attw2_t, __hip_bfloat16* __restrict__ glu_t,
    __hip_bfloat16* __restrict__ bnv, float* __restrict__ loss_out) {
    __shared__ float sPP[2 * ND];
    int blk = blockIdx.x, tid = threadIdx.x;
    if (blk < G_BN) {
        // bnorm: rows emb[1:] L2-normalized -> bf16; padded rows -> 0.
        // 8 rows/block, 32 threads/row, float4 per thread.
        int v = blk * 8 + (tid >> 5);
        int j = (tid & 31) << 2;
        float4 x = make_float4(0.f, 0.f, 0.f, 0.f);
        if (v < NVm1) x = *(const float4*)&emb[((size_t)v + 1) * ND + j];
        float ss = x.x * x.x + x.y * x.y + x.z * x.z + x.w * x.w;
#pragma unroll
        for (int off = 16; off >= 1; off >>= 1) ss += __shfl_xor(ss, off);
        float rn = 1.f / fmaxf(sqrtf(ss), 1e-12f);
        union { ushort4 u4; __hip_bfloat16 h[4]; } o;
        o.h[0] = __float2bfloat16(x.x * rn);
        o.h[1] = __float2bfloat16(x.y * rn);
        o.h[2] = __float2bfloat16(x.z * rn);
        o.h[3] = __float2bfloat16(x.w * rn);
        *(ushort4*)&bnv[(size_t)v * ND + j] = o.u4;
    } else if (blk < G_BN + G_HS) {
        int b = (blk - G_BN) * 2 + (tid >> 7);
        int d = tid & 127;
        float acc = 0.f, msum = 0.f;
        for (int l = 0; l < NL; ++l) {
            float mv = (float)mask[b * NL + l];
            acc += hidden[((size_t)b * NL + l) * ND + d] * mv;
            msum += mv;
        }
        hs[b * ND + d] = acc / msum;
        if (blk == G_BN && tid == 0) loss_out[0] = 0.f;
    } else if (blk < G_BN + G_HS + G_PP) {
        int rel = blk - (G_BN + G_HS);
        int rl = tid >> 7, d = tid & 127;
        int r = rel * 2 + rl;
        sPP[rl * ND + d] = pos_emb[r * ND + d];
        __syncthreads();
        float acc = 0.f;
#pragma unroll 8
        for (int j = 0; j < ND; ++j) acc += sPP[rl * ND + j] * w1[j * ND + d]; // w1 upper half
        posPart[r * ND + d] = acc;
    } else if (blk < G_BN + G_HS + G_PP + G_XB) {
        int rel = blk - (G_BN + G_HS + G_PP);
        size_t base = (size_t)rel * 2048 + (size_t)tid * 8;
        float4 f0 = *(const float4*)&hidden[base];
        float4 f1 = *(const float4*)&hidden[base + 4];
        union { bf16x8 v; __hip_bfloat16 h[8]; } u;
        u.h[0] = __float2bfloat16(f0.x); u.h[1] = __float2bfloat16(f0.y);
        u.h[2] = __float2bfloat16(f0.z); u.h[3] = __float2bfloat16(f0.w);
        u.h[4] = __float2bfloat16(f1.x); u.h[5] = __float2bfloat16(f1.y);
        u.h[6] = __float2bfloat16(f1.z); u.h[7] = __float2bfloat16(f1.w);
        *(bf16x8*)&XbG[base] = u.v;
    } else if (blk < G_BN + G_HS + G_PP + G_XB + G_W1T) {
        int i = (blk - (G_BN + G_HS + G_PP + G_XB)) * 256 + tid;
        int d = i >> 7, j = i & 127;
        w1h_t[d * ND + j] = __float2bfloat16(w1[(ND + j) * ND + d]); // lower (hidden) half
    } else if (blk < G_BN + G_HS + G_PP + G_XB + G_W1T + G_AWT) {
        int i = (blk - (G_BN + G_HS + G_PP + G_XB + G_W1T)) * 256 + tid;
        int d = i >> 7, j = i & 127;
        attw2_t[d * ND + j] = __float2bfloat16(att_w2[j * ND + d]);
    } else {
        int i = (blk - (G_BN + G_HS + G_PP + G_XB + G_W1T + G_AWT)) * 256 + tid;
        int c = i >> 7, j = i & 127;
        glu_t[c * ND + j] = __float2bfloat16(glu1_w[j * 512 + c]);
    }
}

// ---------------- K1: mega — GEMM1(att,nh via MFMA) + alpha + GEMM2(glu) + beta ----------------
__global__ __launch_bounds__(256) void k_mega(
    const __hip_bfloat16* __restrict__ XbG, const __hip_bfloat16* __restrict__ w1h_t,
    const __hip_bfloat16* __restrict__ attw2_t, const __hip_bfloat16* __restrict__ glu_t,
    const float* __restrict__ hs, const float* __restrict__ att_w1,
    const float* __restrict__ att_v, const float* __restrict__ posPart,
    const float* __restrict__ glu1_b, const float* __restrict__ w2,
    const int* __restrict__ mask, float* __restrict__ beta_out) {
    __shared__ __hip_bfloat16 XbS[MR * ND];   // 16 KB swizzled
    __shared__ __hip_bfloat16 WS[ND * ND];    // 32 KB swizzled
    __shared__ __attribute__((aligned(16))) __hip_bfloat16 NHS[MR * 136]; // padded (+8)
    __shared__ float alphaS[MR * NK];
    __shared__ float hsW1S[3 * ND];
    int row0 = blockIdx.x * MR;
    int tid = threadIdx.x;
    int wave = tid >> 6, lane = tid & 63, l16 = lane & 15, quad = lane >> 4;
    int b0 = row0 / NL;

#pragma unroll
    for (int it = 0; it < 4; ++it) {
        int id = it * 256 + tid;
        int row = id >> 4, c = id & 15, gc = c ^ (row & 7);
        gld_lds16((const char*)XbG + ((size_t)(row0 + row) * 16 + gc) * 16,
                  (char*)XbS + (size_t)(it * 256 + wave * 64) * 16);
    }
#pragma unroll
    for (int it = 0; it < 8; ++it) {
        int id = it * 256 + tid;
        int row = id >> 4, c = id & 15, gc = c ^ (row & 7);
        gld_lds16((const char*)attw2_t + ((size_t)row * 16 + gc) * 16,
                  (char*)WS + (size_t)(it * 256 + wave * 64) * 16);
    }
    for (int i = tid; i < 3 * ND; i += 256) {
        int bb = i >> 7, d = i & 127, b = b0 + bb;
        float acc = 0.f;
        if (b < NB) {
            for (int j = 0; j < ND; ++j) acc += hs[b * ND + j] * att_w1[j * ND + d];
        }
        hsW1S[i] = acc;
    }
    __syncthreads();

    const bf16x8* Xv = (const bf16x8*)XbS;
    const bf16x8* Wv = (const bf16x8*)WS;
    const bf16x8* Nv = (const bf16x8*)NHS; // row stride 17 (136 bf16)
    int arow = wave * 16 + l16;

    f32x4 acc8[8];
    // ---- GEMM1-att ----
#pragma unroll
    for (int ni = 0; ni < 8; ++ni) acc8[ni] = (f32x4){0.f, 0.f, 0.f, 0.f};
#pragma unroll
    for (int kk = 0; kk < 4; ++kk) {
        int ko = kk * 4 + quad;
        bf16x8 af = Xv[arow * 16 + (ko ^ (arow & 7))];
#pragma unroll
        for (int ni = 0; ni < 8; ++ni) {
            int n = ni * 16 + l16;
            bf16x8 bf = Wv[n * 16 + (ko ^ (n & 7))];
            acc8[ni] = __builtin_amdgcn_mfma_f32_16x16x32_bf16(af, bf, acc8[ni], 0, 0, 0);
        }
    }
#pragma unroll
    for (int r = 0; r < 4; ++r) {
        int lrow = wave * 16 + quad * 4 + r;
        int grow = row0 + lrow;
        int bb = grow / NL - b0;
        float a0 = 0.f, a1 = 0.f, a2 = 0.f, a3 = 0.f;
#pragma unroll
        for (int ni = 0; ni < 8; ++ni) {
            int col = ni * 16 + l16;
            float atv = fast_tanh(hsW1S[bb * ND + col] + acc8[ni][r]);
            float4 av = *(const float4*)&att_v[col * 4];
            a0 += atv * av.x; a1 += atv * av.y; a2 += atv * av.z; a3 += atv * av.w;
        }
#pragma unroll
        for (int off = 1; off < 16; off <<= 1) {
            a0 += __shfl_xor(a0, off); a1 += __shfl_xor(a1, off);
            a2 += __shfl_xor(a2, off); a3 += __shfl_xor(a3, off);
        }
        if (l16 == 0) {
            alphaS[lrow * 4 + 0] = sigm_fast(a0);
            alphaS[lrow * 4 + 1] = sigm_fast(a1);
            alphaS[lrow * 4 + 2] = sigm_fast(a2);
            alphaS[lrow * 4 + 3] = sigm_fast(a3);
        }
    }
    __syncthreads(); // WS reads done
#pragma unroll
    for (int it = 0; it < 8; ++it) {
        int id = it * 256 + tid;
        int row = id >> 4, c = id & 15, gc = c ^ (row & 7);
        gld_lds16((const char*)w1h_t + ((size_t)row * 16 + gc) * 16,
                  (char*)WS + (size_t)(it * 256 + wave * 64) * 16);
    }
    __syncthreads();
    // ---- GEMM1-nh ----
#pragma unroll
    for (int ni = 0; ni < 8; ++ni) acc8[ni] = (f32x4){0.f, 0.f, 0.f, 0.f};
#pragma unroll
    for (int kk = 0; kk < 4; ++kk) {
        int ko = kk * 4 + quad;
        bf16x8 af = Xv[arow * 16 + (ko ^ (arow & 7))];
#pragma unroll
        for (int ni = 0; ni < 8; ++ni) {
            int n = ni * 16 + l16;
            bf16x8 bf = Wv[n * 16 + (ko ^ (n & 7))];
            acc8[ni] = __builtin_amdgcn_mfma_f32_16x16x32_bf16(af, bf, acc8[ni], 0, 0, 0);
        }
    }
#pragma unroll
    for (int r = 0; r < 4; ++r) {
        int lrow = wave * 16 + quad * 4 + r;
        int grow = row0 + lrow;
        int l = grow % NL;
#pragma unroll
        for (int ni = 0; ni < 8; ++ni) {
            int col = ni * 16 + l16;
            float nhv = fast_tanh(posPart[l * ND + col] + acc8[ni][r]);
            NHS[lrow * 136 + col] = __float2bfloat16(nhv);
        }
    }
    __syncthreads(); // NHS complete, WS free
    // ---- GEMM2: 4 chunks of 128 cols; chunk ch == k-segment ch ----
    for (int ch = 0; ch < 4; ++ch) {
#pragma unroll
        for (int it = 0; it < 8; ++it) {
            int id = it * 256 + tid;
            int row = id >> 4, c = id & 15, gc = c ^ (row & 7);
            gld_lds16((const char*)glu_t + ((size_t)(ch * ND + row) * 16 + gc) * 16,
                      (char*)WS + (size_t)(it * 256 + wave * 64) * 16);
        }
        __syncthreads();
#pragma unroll
        for (int ni = 0; ni < 8; ++ni) acc8[ni] = (f32x4){0.f, 0.f, 0.f, 0.f};
#pragma unroll
        for (int kk = 0; kk < 4; ++kk) {
            int ko = kk * 4 + quad;
            bf16x8 af = Nv[arow * 17 + ko]; // padded, no swizzle
#pragma unroll
            for (int ni = 0; ni < 8; ++ni) {
                int n = ni * 16 + l16;
                bf16x8 bf = Wv[n * 16 + (ko ^ (n & 7))];
                acc8[ni] = __builtin_amdgcn_mfma_f32_16x16x32_bf16(af, bf, acc8[ni], 0, 0, 0);
            }
        }
#pragma unroll
        for (int r = 0; r < 4; ++r) {
            float s = 0.f;
#pragma unroll
            for (int ni = 0; ni < 8; ++ni) {
                int col = ni * 16 + l16;
                s += sigm_fast(acc8[ni][r] + glu1_b[ch * ND + col]) * w2[col * 4 + ch];
            }
#pragma unroll
            for (int off = 1; off < 16; off <<= 1) s += __shfl_xor(s, off);
            if (l16 == 0) {
                int lrow = wave * 16 + quad * 4 + r;
                int grow = row0 + lrow;
                float a = alphaS[lrow * 4 + ch];
                beta_out[(size_t)grow * 4 + ch] = s * (0.5f + a) * (float)mask[grow];
            }
        }
        __syncthreads();
    }
}

// ---------------- K2: loss (lens inline, atomic accumulate) ----------------
__global__ void k_loss(const float* __restrict__ beta, const int* __restrict__ mask,
                       float* __restrict__ loss_out) {
    int b = blockIdx.x;
    int t = threadIdx.x; // 64
    float mv = (t < NL) ? (float)mask[b * NL + t] : 0.f;
    float msum = mv;
    for (int off = 32; off >= 1; off >>= 1) msum += __shfl_xor(msum, off);
    float lens = msum - 5.0f; // LENGTH=5
    float bk[NK] = {0.f, 0.f, 0.f, 0.f};
    if (t < NL) {
#pragma unroll
        for (int k = 0; k < NK; ++k) bk[k] = beta[((size_t)b * NL + t) * NK + k];
    }
    float nb[NK];
#pragma unroll
    for (int k = 0; k < NK; ++k) {
        float v = bk[k] * bk[k];
        for (int off = 32; off >= 1; off >>= 1) v += __shfl_xor(v, off);
        nb[k] = bk[k] / fmaxf(sqrtf(v), 1e-12f);
    }
    float sim = 0.f;
#pragma unroll
    for (int i = 0; i < NK; ++i) {
#pragma unroll
        for (int j = 0; j < NK; ++j) {
            if (j > i) {
                float p = nb[i] * nb[j];
                for (int off = 32; off >= 1; off >>= 1) p += __shfl_xor(p, off);
                sim += fabsf(p);
            }
        }
    }
    sim *= (2.0f / (NK * (NK - 1)));
    if (t == 0) atomicAdd(loss_out, sigm_prec(sim * lens) * 0.01f); // BETA
}

// ---------------- K3: select -> bf16 (2 b per block) ----------------
__global__ __launch_bounds__(256) void k_select(
    const float* __restrict__ beta, const float* __restrict__ hidden,
    __hip_bfloat16* __restrict__ selb) {
    int b = blockIdx.x * 2 + (threadIdx.x >> 7);
    int d = threadIdx.x & 127;
    float a0 = 0.f, a1 = 0.f, a2 = 0.f, a3 = 0.f;
    for (int l = 0; l < NL; ++l) {
        float h = hidden[((size_t)b * NL + l) * ND + d];
        float4 bv = *(const float4*)&beta[((size_t)b * NL + l) * NK];
        a0 = fmaf(bv.x, h, a0);
        a1 = fmaf(bv.y, h, a1);
        a2 = fmaf(bv.z, h, a2);
        a3 = fmaf(bv.w, h, a3);
    }
    selb[((size_t)b * NK + 0) * ND + d] = __float2bfloat16(a0);
    selb[((size_t)b * NK + 1) * ND + d] = __float2bfloat16(a1);
    selb[((size_t)b * NK + 2) * ND + d] = __float2bfloat16(a2);
    selb[((size_t)b * NK + 3) * ND + d] = __float2bfloat16(a3);
}

// ---------------- K4: big GEMM  C[1024,NPAD2] = selb @ bnv^T ----------------
// Store-bound kernel (256 MB fp32 out). 64-row B chunks, double-buffered, one-deep
// prefetch. Full blocks use raw s_barrier with COUNTED vmcnt(40): the 40 scores/maxs
// stores per lane per chunk stay in flight across the barrier; only the 4 prefetch
// global_load_lds (issued BEFORE the stores, fenced by sched_barrier) are drained.
// Edge block (n-guard makes store count non-uniform) falls back to __syncthreads().
__global__ __launch_bounds__(256) void k_gemm(
    const __hip_bfloat16* __restrict__ selb, const __hip_bfloat16* __restrict__ bn,
    float* __restrict__ scores, float* __restrict__ maxs) {
    __shared__ __attribute__((aligned(16))) __hip_bfloat16 As[128 * 128];    // 32 KB
    __shared__ __attribute__((aligned(16))) __hip_bfloat16 Bs[2][64 * 128];  // 2x16 KB
    int bm0 = blockIdx.y * 128;
    int nbase = blockIdx.x * GEMM_NSPAN;
    int tid = threadIdx.x;
    int wave = tid >> 6, lane = tid & 63;
    int l16 = lane & 15, quad = lane >> 4;
    int m_loc = wave * 32; // 4-way m split: wave owns 32 m-rows x all 64 n of chunk
    bool full = (nbase + GEMM_NSPAN) <= NVm1;
    const size_t SC_K = (size_t)NB * NVm1;

#pragma unroll
    for (int it = 0; it < 8; ++it) {
        int id = it * 256 + tid;
        int row = id >> 4, c = id & 15, gc = c ^ (row & 7);
        gld_lds16((const char*)selb + ((size_t)(bm0 + row) * 16 + gc) * 16,
                  (char*)As + (size_t)(it * 256 + wave * 64) * 16);
    }
#pragma unroll
    for (int it = 0; it < 4; ++it) {
        int id = it * 256 + tid;
        int row = id >> 4, c = id & 15, gc = c ^ (row & 7);
        gld_lds16((const char*)bn + ((size_t)(nbase + row) * 16 + gc) * 16,
                  (char*)Bs[0] + (size_t)(it * 256 + wave * 64) * 16);
    }
    __syncthreads();

    const bf16x8* Av = (const bf16x8*)As;

#pragma unroll
    for (int ch = 0; ch < 8; ++ch) {
        // prefetch next chunk (fire-and-forget; drained at the counted barrier)
        if (ch < 7) {
            int bn0 = nbase + (ch + 1) * 64;
#pragma unroll
            for (int it = 0; it < 4; ++it) {
                int id = it * 256 + tid;
                int row = id >> 4, c = id & 15, gc = c ^ (row & 7);
                gld_lds16((const char*)bn + ((size_t)(bn0 + row) * 16 + gc) * 16,
                          (char*)Bs[(ch + 1) & 1] + (size_t)(it * 256 + wave * 64) * 16);
            }
            // keep the 4 glds issued before any store (vmcnt count relies on order)
            __builtin_amdgcn_sched_barrier(0);
        }
        const bf16x8* Bv = (const bf16x8*)Bs[ch & 1];
        f32x4 acc[2][4];
#pragma unroll
        for (int mi = 0; mi < 2; ++mi)
#pragma unroll
            for (int ni = 0; ni < 4; ++ni) acc[mi][ni] = (f32x4){0.f, 0.f, 0.f, 0.f};

#pragma unroll
        for (int kk = 0; kk < 4; ++kk) {
            int ko = kk * 4 + quad;
            bf16x8 afr[2], bfr[4];
#pragma unroll
            for (int mi = 0; mi < 2; ++mi) {
                int row = m_loc + mi * 16 + l16;
                afr[mi] = Av[row * 16 + (ko ^ (row & 7))];
            }
#pragma unroll
            for (int ni = 0; ni < 4; ++ni) {
                int row = ni * 16 + l16;
                bfr[ni] = Bv[row * 16 + (ko ^ (row & 7))];
            }
#pragma unroll
            for (int mi = 0; mi < 2; ++mi)
#pragma unroll
                for (int ni = 0; ni < 4; ++ni)
                    acc[mi][ni] = __builtin_amdgcn_mfma_f32_16x16x32_bf16(
                        afr[mi], bfr[ni], acc[mi][ni], 0, 0, 0);
        }

        // epilogue: 8 tiles x (4 scores + 1 maxs) = 40 nontemporal dword stores/lane
        int ncol0 = nbase + ch * 64;
#pragma unroll
        for (int mi = 0; mi < 2; ++mi) {
            int m_base = bm0 + m_loc + mi * 16;
            int bidx = (m_base >> 2) + quad;
#pragma unroll
            for (int ni = 0; ni < 4; ++ni) {
                int n = ncol0 + ni * 16 + l16;
                if (full || n < NVm1) {
                    float mx = acc[mi][ni][0];
#pragma unroll
                    for (int r = 0; r < 4; ++r) {
                        float val = acc[mi][ni][r];
                        __builtin_nontemporal_store(
                            val, &scores[(size_t)r * SC_K + (size_t)bidx * NVm1 + n]);
                        mx = fmaxf(mx, val);
                    }
                    __builtin_nontemporal_store(mx, &maxs[(size_t)bidx * NVm1 + n]);
                }
            }
        }

        if (ch < 7) {
            if (full) {
                // drain only the 4 prefetch glds (40 stores may stay outstanding);
                // lgkmcnt(0): this wave's ds_reads of Bs done before others restage it
                asm volatile("s_waitcnt vmcnt(40) lgkmcnt(0)" ::: "memory");
                __builtin_amdgcn_s_barrier();
            } else {
                __syncthreads();
            }
        }
    }
}

extern "C" void kernel_launch(void* const* d_in, const int* in_sizes, int n_in,
                              void* d_out, int out_size, void* d_ws, size_t ws_size,
                              hipStream_t stream) {
    const float* hidden  = (const float*)d_in[0];
    const int*   mask    = (const int*)d_in[1];
    const float* pos_emb = (const float*)d_in[2];
    const float* w1      = (const float*)d_in[3];
    const float* w2      = (const float*)d_in[4];
    const float* glu1_w  = (const float*)d_in[5];
    const float* glu1_b  = (const float*)d_in[6];
    const float* att_w1  = (const float*)d_in[7];
    const float* att_w2  = (const float*)d_in[8];
    const float* att_v   = (const float*)d_in[9];
    const float* emb     = (const float*)d_in[10];

    float* out      = (float*)d_out;
    float* max_out  = out;                                   // [B, NVm1]
    float* loss_out = out + (size_t)NB * NVm1;               // scalar
    float* scores   = out + (size_t)NB * NVm1 + 1;           // [K, B, NVm1]

    char* w = (char*)d_ws;
    auto alloc = [&](size_t bytes) {
        char* p = w;
        w += (bytes + 255) & ~(size_t)255;
        return p;
    };
    float* posPart = (float*)alloc((size_t)NL * ND * 4);
    float* hs      = (float*)alloc((size_t)NB * ND * 4);
    float* betav   = (float*)alloc((size_t)ROWS * NK * 4);
    __hip_bfloat16* XbG     = (__hip_bfloat16*)alloc((size_t)ROWS * ND * 2);
    __hip_bfloat16* w1h_t   = (__hip_bfloat16*)alloc((size_t)ND * ND * 2);
    __hip_bfloat16* attw2_t = (__hip_bfloat16*)alloc((size_t)ND * ND * 2);
    __hip_bfloat16* glu_t   = (__hip_bfloat16*)alloc((size_t)512 * ND * 2);
    __hip_bfloat16* selb    = (__hip_bfloat16*)alloc((size_t)MROWS * ND * 2);
    __hip_bfloat16* bnv     = (__hip_bfloat16*)alloc((size_t)NPAD2 * ND * 2);

    k_prep<<<G_TOT, 256, 0, stream>>>(hidden, mask, pos_emb, w1, att_w2, glu1_w, emb,
                                      hs, posPart, XbG, w1h_t, attw2_t, glu_t, bnv, loss_out);
    k_mega<<<ROWS / MR, 256, 0, stream>>>(XbG, w1h_t, attw2_t, glu_t, hs, att_w1,
                                          att_v, posPart, glu1_b, w2, mask, betav);
    k_loss<<<NB, 64, 0, stream>>>(betav, mask, loss_out);
    k_select<<<NB / 2, 256, 0, stream>>>(betav, hidden, selb);
    k_gemm<<<dim3(NPAD2 / GEMM_NSPAN, MROWS / 128), 256, 0, stream>>>(selb, bnv, scores, max_out);
}

// Round 2
// 432.380 us; speedup vs baseline: 1.3404x; 1.3404x over previous
//
#include <hip/hip_runtime.h>
#include <hip/hip_bf16.h>
#include <math.h>

// Problem constants
constexpr int NB = 256;      // batch
constexpr int NL = 50;       // seq len
constexpr int ND = 128;      // dim
constexpr int NK = 4;        // interests
constexpr int NVm1 = 49999;  // V-1
constexpr int NPAD2 = 50176; // N padded to 392*128
constexpr int ROWS = NB * NL;   // 12800
constexpr int MROWS = NB * NK;  // 1024 (rows of select, b-major: row = b*4+k)
constexpr int GEMM_NSPAN = 512; // n cols per block in big GEMM (8 chunks of 64)
constexpr int MR = 64;          // rows per mega block

// prep kernel block ranges
constexpr int G_BN  = NPAD2 / 8;  // 6272 bnorm (8 rows/blk, float4 per thread)
constexpr int G_HS  = NB / 2;     // 128 hs (2 b/blk)
constexpr int G_PP  = NL / 2;     // 25 posPart (2 rows/blk)
constexpr int G_XB  = ROWS * ND / 2048; // 800 Xb cast
constexpr int G_W1T = ND * ND / 256;    // 64
constexpr int G_AWT = ND * ND / 256;    // 64
constexpr int G_GLT = ND * 512 / 256;   // 256
constexpr int G_TOT = G_BN + G_HS + G_PP + G_XB + G_W1T + G_AWT + G_GLT;

typedef __bf16 bf16x8 __attribute__((ext_vector_type(8)));
typedef float f32x4 __attribute__((ext_vector_type(4)));

__device__ __forceinline__ float sigm_fast(float x) { return 1.0f / (1.0f + __expf(-x)); }
__device__ __forceinline__ float sigm_prec(float x) { return 1.0f / (1.0f + expf(-x)); }
__device__ __forceinline__ float fast_tanh(float x) {
    float xc = fminf(fmaxf(x, -15.f), 15.f);
    float e = __expf(2.f * xc);
    return (e - 1.f) / (e + 1.f);
}

__device__ __forceinline__ void gld_lds16(const void* g, void* l) {
    __builtin_amdgcn_global_load_lds(
        (const __attribute__((address_space(1))) void*)g,
        (__attribute__((address_space(3))) void*)l, 16, 0, 0);
}

// ---------------- K0: prep — bnorm, hs, posPart, Xb cast, weight transposes ----------------
__global__ __launch_bounds__(256) void k_prep(
    const float* __restrict__ hidden, const int* __restrict__ mask,
    const float* __restrict__ pos_emb, const float* __restrict__ w1,
    const float* __restrict__ att_w2, const float* __restrict__ glu1_w,
    const float* __restrict__ emb,
    float* __restrict__ hs, float* __restrict__ posPart,
    __hip_bfloat16* __restrict__ XbG, __hip_bfloat16* __restrict__ w1h_t,
    __hip_bfloat16* __restrict__ attw2_t, __hip_bfloat16* __restrict__ glu_t,
    __hip_bfloat16* __restrict__ bnv, float* __restrict__ loss_out) {
    __shared__ float sPP[2 * ND];
    int blk = blockIdx.x, tid = threadIdx.x;
    if (blk < G_BN) {
        // bnorm: rows emb[1:] L2-normalized -> bf16; padded rows -> 0.
        // 8 rows/block, 32 threads/row, float4 per thread.
        int v = blk * 8 + (tid >> 5);
        int j = (tid & 31) << 2;
        float4 x = make_float4(0.f, 0.f, 0.f, 0.f);
        if (v < NVm1) x = *(const float4*)&emb[((size_t)v + 1) * ND + j];
        float ss = x.x * x.x + x.y * x.y + x.z * x.z + x.w * x.w;
#pragma unroll
        for (int off = 16; off >= 1; off >>= 1) ss += __shfl_xor(ss, off);
        float rn = 1.f / fmaxf(sqrtf(ss), 1e-12f);
        union { ushort4 u4; __hip_bfloat16 h[4]; } o;
        o.h[0] = __float2bfloat16(x.x * rn);
        o.h[1] = __float2bfloat16(x.y * rn);
        o.h[2] = __float2bfloat16(x.z * rn);
        o.h[3] = __float2bfloat16(x.w * rn);
        *(ushort4*)&bnv[(size_t)v * ND + j] = o.u4;
    } else if (blk < G_BN + G_HS) {
        int b = (blk - G_BN) * 2 + (tid >> 7);
        int d = tid & 127;
        float acc = 0.f, msum = 0.f;
        for (int l = 0; l < NL; ++l) {
            float mv = (float)mask[b * NL + l];
            acc += hidden[((size_t)b * NL + l) * ND + d] * mv;
            msum += mv;
        }
        hs[b * ND + d] = acc / msum;
        if (blk == G_BN && tid == 0) loss_out[0] = 0.f;
    } else if (blk < G_BN + G_HS + G_PP) {
        int rel = blk - (G_BN + G_HS);
        int rl = tid >> 7, d = tid & 127;
        int r = rel * 2 + rl;
        sPP[rl * ND + d] = pos_emb[r * ND + d];
        __syncthreads();
        float acc = 0.f;
#pragma unroll 8
        for (int j = 0; j < ND; ++j) acc += sPP[rl * ND + j] * w1[j * ND + d]; // w1 upper half
        posPart[r * ND + d] = acc;
    } else if (blk < G_BN + G_HS + G_PP + G_XB) {
        int rel = blk - (G_BN + G_HS + G_PP);
        size_t base = (size_t)rel * 2048 + (size_t)tid * 8;
        float4 f0 = *(const float4*)&hidden[base];
        float4 f1 = *(const float4*)&hidden[base + 4];
        union { bf16x8 v; __hip_bfloat16 h[8]; } u;
        u.h[0] = __float2bfloat16(f0.x); u.h[1] = __float2bfloat16(f0.y);
        u.h[2] = __float2bfloat16(f0.z); u.h[3] = __float2bfloat16(f0.w);
        u.h[4] = __float2bfloat16(f1.x); u.h[5] = __float2bfloat16(f1.y);
        u.h[6] = __float2bfloat16(f1.z); u.h[7] = __float2bfloat16(f1.w);
        *(bf16x8*)&XbG[base] = u.v;
    } else if (blk < G_BN + G_HS + G_PP + G_XB + G_W1T) {
        int i = (blk - (G_BN + G_HS + G_PP + G_XB)) * 256 + tid;
        int d = i >> 7, j = i & 127;
        w1h_t[d * ND + j] = __float2bfloat16(w1[(ND + j) * ND + d]); // lower (hidden) half
    } else if (blk < G_BN + G_HS + G_PP + G_XB + G_W1T + G_AWT) {
        int i = (blk - (G_BN + G_HS + G_PP + G_XB + G_W1T)) * 256 + tid;
        int d = i >> 7, j = i & 127;
        attw2_t[d * ND + j] = __float2bfloat16(att_w2[j * ND + d]);
    } else {
        int i = (blk - (G_BN + G_HS + G_PP + G_XB + G_W1T + G_AWT)) * 256 + tid;
        int c = i >> 7, j = i & 127;
        glu_t[c * ND + j] = __float2bfloat16(glu1_w[j * 512 + c]);
    }
}

// ---------------- K1: mega — GEMM1(att,nh via MFMA) + alpha + GEMM2(glu) + beta ----------------
__global__ __launch_bounds__(256) void k_mega(
    const __hip_bfloat16* __restrict__ XbG, const __hip_bfloat16* __restrict__ w1h_t,
    const __hip_bfloat16* __restrict__ attw2_t, const __hip_bfloat16* __restrict__ glu_t,
    const float* __restrict__ hs, const float* __restrict__ att_w1,
    const float* __restrict__ att_v, const float* __restrict__ posPart,
    const float* __restrict__ glu1_b, const float* __restrict__ w2,
    const int* __restrict__ mask, float* __restrict__ beta_out) {
    __shared__ __hip_bfloat16 XbS[MR * ND];   // 16 KB swizzled
    __shared__ __hip_bfloat16 WS[ND * ND];    // 32 KB swizzled
    __shared__ __attribute__((aligned(16))) __hip_bfloat16 NHS[MR * 136]; // padded (+8)
    __shared__ float alphaS[MR * NK];
    __shared__ float hsW1S[3 * ND];
    int row0 = blockIdx.x * MR;
    int tid = threadIdx.x;
    int wave = tid >> 6, lane = tid & 63, l16 = lane & 15, quad = lane >> 4;
    int b0 = row0 / NL;

#pragma unroll
    for (int it = 0; it < 4; ++it) {
        int id = it * 256 + tid;
        int row = id >> 4, c = id & 15, gc = c ^ (row & 7);
        gld_lds16((const char*)XbG + ((size_t)(row0 + row) * 16 + gc) * 16,
                  (char*)XbS + (size_t)(it * 256 + wave * 64) * 16);
    }
#pragma unroll
    for (int it = 0; it < 8; ++it) {
        int id = it * 256 + tid;
        int row = id >> 4, c = id & 15, gc = c ^ (row & 7);
        gld_lds16((const char*)attw2_t + ((size_t)row * 16 + gc) * 16,
                  (char*)WS + (size_t)(it * 256 + wave * 64) * 16);
    }
    for (int i = tid; i < 3 * ND; i += 256) {
        int bb = i >> 7, d = i & 127, b = b0 + bb;
        float acc = 0.f;
        if (b < NB) {
            for (int j = 0; j < ND; ++j) acc += hs[b * ND + j] * att_w1[j * ND + d];
        }
        hsW1S[i] = acc;
    }
    __syncthreads();

    const bf16x8* Xv = (const bf16x8*)XbS;
    const bf16x8* Wv = (const bf16x8*)WS;
    const bf16x8* Nv = (const bf16x8*)NHS; // row stride 17 (136 bf16)
    int arow = wave * 16 + l16;

    f32x4 acc8[8];
    // ---- GEMM1-att ----
#pragma unroll
    for (int ni = 0; ni < 8; ++ni) acc8[ni] = (f32x4){0.f, 0.f, 0.f, 0.f};
#pragma unroll
    for (int kk = 0; kk < 4; ++kk) {
        int ko = kk * 4 + quad;
        bf16x8 af = Xv[arow * 16 + (ko ^ (arow & 7))];
#pragma unroll
        for (int ni = 0; ni < 8; ++ni) {
            int n = ni * 16 + l16;
            bf16x8 bf = Wv[n * 16 + (ko ^ (n & 7))];
            acc8[ni] = __builtin_amdgcn_mfma_f32_16x16x32_bf16(af, bf, acc8[ni], 0, 0, 0);
        }
    }
#pragma unroll
    for (int r = 0; r < 4; ++r) {
        int lrow = wave * 16 + quad * 4 + r;
        int grow = row0 + lrow;
        int bb = grow / NL - b0;
        float a0 = 0.f, a1 = 0.f, a2 = 0.f, a3 = 0.f;
#pragma unroll
        for (int ni = 0; ni < 8; ++ni) {
            int col = ni * 16 + l16;
            float atv = fast_tanh(hsW1S[bb * ND + col] + acc8[ni][r]);
            float4 av = *(const float4*)&att_v[col * 4];
            a0 += atv * av.x; a1 += atv * av.y; a2 += atv * av.z; a3 += atv * av.w;
        }
#pragma unroll
        for (int off = 1; off < 16; off <<= 1) {
            a0 += __shfl_xor(a0, off); a1 += __shfl_xor(a1, off);
            a2 += __shfl_xor(a2, off); a3 += __shfl_xor(a3, off);
        }
        if (l16 == 0) {
            alphaS[lrow * 4 + 0] = sigm_fast(a0);
            alphaS[lrow * 4 + 1] = sigm_fast(a1);
            alphaS[lrow * 4 + 2] = sigm_fast(a2);
            alphaS[lrow * 4 + 3] = sigm_fast(a3);
        }
    }
    __syncthreads(); // WS reads done
#pragma unroll
    for (int it = 0; it < 8; ++it) {
        int id = it * 256 + tid;
        int row = id >> 4, c = id & 15, gc = c ^ (row & 7);
        gld_lds16((const char*)w1h_t + ((size_t)row * 16 + gc) * 16,
                  (char*)WS + (size_t)(it * 256 + wave * 64) * 16);
    }
    __syncthreads();
    // ---- GEMM1-nh ----
#pragma unroll
    for (int ni = 0; ni < 8; ++ni) acc8[ni] = (f32x4){0.f, 0.f, 0.f, 0.f};
#pragma unroll
    for (int kk = 0; kk < 4; ++kk) {
        int ko = kk * 4 + quad;
        bf16x8 af = Xv[arow * 16 + (ko ^ (arow & 7))];
#pragma unroll
        for (int ni = 0; ni < 8; ++ni) {
            int n = ni * 16 + l16;
            bf16x8 bf = Wv[n * 16 + (ko ^ (n & 7))];
            acc8[ni] = __builtin_amdgcn_mfma_f32_16x16x32_bf16(af, bf, acc8[ni], 0, 0, 0);
        }
    }
#pragma unroll
    for (int r = 0; r < 4; ++r) {
        int lrow = wave * 16 + quad * 4 + r;
        int grow = row0 + lrow;
        int l = grow % NL;
#pragma unroll
        for (int ni = 0; ni < 8; ++ni) {
            int col = ni * 16 + l16;
            float nhv = fast_tanh(posPart[l * ND + col] + acc8[ni][r]);
            NHS[lrow * 136 + col] = __float2bfloat16(nhv);
        }
    }
    __syncthreads(); // NHS complete, WS free
    // ---- GEMM2: 4 chunks of 128 cols; chunk ch == k-segment ch ----
    for (int ch = 0; ch < 4; ++ch) {
#pragma unroll
        for (int it = 0; it < 8; ++it) {
            int id = it * 256 + tid;
            int row = id >> 4, c = id & 15, gc = c ^ (row & 7);
            gld_lds16((const char*)glu_t + ((size_t)(ch * ND + row) * 16 + gc) * 16,
                      (char*)WS + (size_t)(it * 256 + wave * 64) * 16);
        }
        __syncthreads();
#pragma unroll
        for (int ni = 0; ni < 8; ++ni) acc8[ni] = (f32x4){0.f, 0.f, 0.f, 0.f};
#pragma unroll
        for (int kk = 0; kk < 4; ++kk) {
            int ko = kk * 4 + quad;
            bf16x8 af = Nv[arow * 17 + ko]; // padded, no swizzle
#pragma unroll
            for (int ni = 0; ni < 8; ++ni) {
                int n = ni * 16 + l16;
                bf16x8 bf = Wv[n * 16 + (ko ^ (n & 7))];
                acc8[ni] = __builtin_amdgcn_mfma_f32_16x16x32_bf16(af, bf, acc8[ni], 0, 0, 0);
            }
        }
#pragma unroll
        for (int r = 0; r < 4; ++r) {
            float s = 0.f;
#pragma unroll
            for (int ni = 0; ni < 8; ++ni) {
                int col = ni * 16 + l16;
                s += sigm_fast(acc8[ni][r] + glu1_b[ch * ND + col]) * w2[col * 4 + ch];
            }
#pragma unroll
            for (int off = 1; off < 16; off <<= 1) s += __shfl_xor(s, off);
            if (l16 == 0) {
                int lrow = wave * 16 + quad * 4 + r;
                int grow = row0 + lrow;
                float a = alphaS[lrow * 4 + ch];
                beta_out[(size_t)grow * 4 + ch] = s * (0.5f + a) * (float)mask[grow];
            }
        }
        __syncthreads();
    }
}

// ---------------- K2: loss (lens inline, atomic accumulate) ----------------
__global__ void k_loss(const float* __restrict__ beta, const int* __restrict__ mask,
                       float* __restrict__ loss_out) {
    int b = blockIdx.x;
    int t = threadIdx.x; // 64
    float mv = (t < NL) ? (float)mask[b * NL + t] : 0.f;
    float msum = mv;
    for (int off = 32; off >= 1; off >>= 1) msum += __shfl_xor(msum, off);
    float lens = msum - 5.0f; // LENGTH=5
    float bk[NK] = {0.f, 0.f, 0.f, 0.f};
    if (t < NL) {
#pragma unroll
        for (int k = 0; k < NK; ++k) bk[k] = beta[((size_t)b * NL + t) * NK + k];
    }
    float nb[NK];
#pragma unroll
    for (int k = 0; k < NK; ++k) {
        float v = bk[k] * bk[k];
        for (int off = 32; off >= 1; off >>= 1) v += __shfl_xor(v, off);
        nb[k] = bk[k] / fmaxf(sqrtf(v), 1e-12f);
    }
    float sim = 0.f;
#pragma unroll
    for (int i = 0; i < NK; ++i) {
#pragma unroll
        for (int j = 0; j < NK; ++j) {
            if (j > i) {
                float p = nb[i] * nb[j];
                for (int off = 32; off >= 1; off >>= 1) p += __shfl_xor(p, off);
                sim += fabsf(p);
            }
        }
    }
    sim *= (2.0f / (NK * (NK - 1)));
    if (t == 0) atomicAdd(loss_out, sigm_prec(sim * lens) * 0.01f); // BETA
}

// ---------------- K3: select -> bf16 (2 b per block) ----------------
__global__ __launch_bounds__(256) void k_select(
    const float* __restrict__ beta, const float* __restrict__ hidden,
    __hip_bfloat16* __restrict__ selb) {
    int b = blockIdx.x * 2 + (threadIdx.x >> 7);
    int d = threadIdx.x & 127;
    float a0 = 0.f, a1 = 0.f, a2 = 0.f, a3 = 0.f;
    for (int l = 0; l < NL; ++l) {
        float h = hidden[((size_t)b * NL + l) * ND + d];
        float4 bv = *(const float4*)&beta[((size_t)b * NL + l) * NK];
        a0 = fmaf(bv.x, h, a0);
        a1 = fmaf(bv.y, h, a1);
        a2 = fmaf(bv.z, h, a2);
        a3 = fmaf(bv.w, h, a3);
    }
    selb[((size_t)b * NK + 0) * ND + d] = __float2bfloat16(a0);
    selb[((size_t)b * NK + 1) * ND + d] = __float2bfloat16(a1);
    selb[((size_t)b * NK + 2) * ND + d] = __float2bfloat16(a2);
    selb[((size_t)b * NK + 3) * ND + d] = __float2bfloat16(a3);
}

// ---------------- K4: big GEMM  C[1024,NPAD2] = selb @ bnv^T ----------------
// Store-bound kernel (256 MB fp32 out). 64-row B chunks, double-buffered, one-deep
// prefetch. Full blocks use raw s_barrier with COUNTED vmcnt(40): the 40 scores/maxs
// stores per lane per chunk stay in flight across the barrier; only the 4 prefetch
// global_load_lds (issued BEFORE the stores, fenced by sched_barrier) are drained.
// Stores are PLAIN (L2 write-allocate): scores row stride (199996 B) is 128B-
// misaligned, so partial 64B segments MUST merge in L2 — nontemporal stores caused
// 1.74x HBM write amplification and 3x slowdown (round-1 post-mortem).
// Edge block (n-guard makes store count non-uniform) falls back to __syncthreads().
__global__ __launch_bounds__(256) void k_gemm(
    const __hip_bfloat16* __restrict__ selb, const __hip_bfloat16* __restrict__ bn,
    float* __restrict__ scores, float* __restrict__ maxs) {
    __shared__ __attribute__((aligned(16))) __hip_bfloat16 As[128 * 128];    // 32 KB
    __shared__ __attribute__((aligned(16))) __hip_bfloat16 Bs[2][64 * 128];  // 2x16 KB
    int bm0 = blockIdx.y * 128;
    int nbase = blockIdx.x * GEMM_NSPAN;
    int tid = threadIdx.x;
    int wave = tid >> 6, lane = tid & 63;
    int l16 = lane & 15, quad = lane >> 4;
    int m_loc = wave * 32; // 4-way m split: wave owns 32 m-rows x all 64 n of chunk
    bool full = (nbase + GEMM_NSPAN) <= NVm1;
    const size_t SC_K = (size_t)NB * NVm1;

#pragma unroll
    for (int it = 0; it < 8; ++it) {
        int id = it * 256 + tid;
        int row = id >> 4, c = id & 15, gc = c ^ (row & 7);
        gld_lds16((const char*)selb + ((size_t)(bm0 + row) * 16 + gc) * 16,
                  (char*)As + (size_t)(it * 256 + wave * 64) * 16);
    }
#pragma unroll
    for (int it = 0; it < 4; ++it) {
        int id = it * 256 + tid;
        int row = id >> 4, c = id & 15, gc = c ^ (row & 7);
        gld_lds16((const char*)bn + ((size_t)(nbase + row) * 16 + gc) * 16,
                  (char*)Bs[0] + (size_t)(it * 256 + wave * 64) * 16);
    }
    __syncthreads();

    const bf16x8* Av = (const bf16x8*)As;

#pragma unroll
    for (int ch = 0; ch < 8; ++ch) {
        // prefetch next chunk (fire-and-forget; drained at the counted barrier)
        if (ch < 7) {
            int bn0 = nbase + (ch + 1) * 64;
#pragma unroll
            for (int it = 0; it < 4; ++it) {
                int id = it * 256 + tid;
                int row = id >> 4, c = id & 15, gc = c ^ (row & 7);
                gld_lds16((const char*)bn + ((size_t)(bn0 + row) * 16 + gc) * 16,
                          (char*)Bs[(ch + 1) & 1] + (size_t)(it * 256 + wave * 64) * 16);
            }
            // keep the 4 glds issued before any store (vmcnt count relies on order)
            __builtin_amdgcn_sched_barrier(0);
        }
        const bf16x8* Bv = (const bf16x8*)Bs[ch & 1];
        f32x4 acc[2][4];
#pragma unroll
        for (int mi = 0; mi < 2; ++mi)
#pragma unroll
            for (int ni = 0; ni < 4; ++ni) acc[mi][ni] = (f32x4){0.f, 0.f, 0.f, 0.f};

#pragma unroll
        for (int kk = 0; kk < 4; ++kk) {
            int ko = kk * 4 + quad;
            bf16x8 afr[2], bfr[4];
#pragma unroll
            for (int mi = 0; mi < 2; ++mi) {
                int row = m_loc + mi * 16 + l16;
                afr[mi] = Av[row * 16 + (ko ^ (row & 7))];
            }
#pragma unroll
            for (int ni = 0; ni < 4; ++ni) {
                int row = ni * 16 + l16;
                bfr[ni] = Bv[row * 16 + (ko ^ (row & 7))];
            }
#pragma unroll
            for (int mi = 0; mi < 2; ++mi)
#pragma unroll
                for (int ni = 0; ni < 4; ++ni)
                    acc[mi][ni] = __builtin_amdgcn_mfma_f32_16x16x32_bf16(
                        afr[mi], bfr[ni], acc[mi][ni], 0, 0, 0);
        }

        // epilogue: 8 tiles x (4 scores + 1 maxs) = 40 plain dword stores/lane
        int ncol0 = nbase + ch * 64;
#pragma unroll
        for (int mi = 0; mi < 2; ++mi) {
            int m_base = bm0 + m_loc + mi * 16;
            int bidx = (m_base >> 2) + quad;
#pragma unroll
            for (int ni = 0; ni < 4; ++ni) {
                int n = ncol0 + ni * 16 + l16;
                if (full || n < NVm1) {
                    float mx = acc[mi][ni][0];
#pragma unroll
                    for (int r = 0; r < 4; ++r) {
                        float val = acc[mi][ni][r];
                        scores[(size_t)r * SC_K + (size_t)bidx * NVm1 + n] = val;
                        mx = fmaxf(mx, val);
                    }
                    maxs[(size_t)bidx * NVm1 + n] = mx;
                }
            }
        }

        if (ch < 7) {
            if (full) {
                // drain only the 4 prefetch glds (40 stores may stay outstanding);
                // lgkmcnt(0): this wave's ds_reads of Bs done before others restage it
                asm volatile("s_waitcnt vmcnt(40) lgkmcnt(0)" ::: "memory");
                __builtin_amdgcn_s_barrier();
            } else {
                __syncthreads();
            }
        }
    }
}

extern "C" void kernel_launch(void* const* d_in, const int* in_sizes, int n_in,
                              void* d_out, int out_size, void* d_ws, size_t ws_size,
                              hipStream_t stream) {
    const float* hidden  = (const float*)d_in[0];
    const int*   mask    = (const int*)d_in[1];
    const float* pos_emb = (const float*)d_in[2];
    const float* w1      = (const float*)d_in[3];
    const float* w2      = (const float*)d_in[4];
    const float* glu1_w  = (const float*)d_in[5];
    const float* glu1_b  = (const float*)d_in[6];
    const float* att_w1  = (const float*)d_in[7];
    const float* att_w2  = (const float*)d_in[8];
    const float* att_v   = (const float*)d_in[9];
    const float* emb     = (const float*)d_in[10];

    float* out      = (float*)d_out;
    float* max_out  = out;                                   // [B, NVm1]
    float* loss_out = out + (size_t)NB * NVm1;               // scalar
    float* scores   = out + (size_t)NB * NVm1 + 1;           // [K, B, NVm1]

    char* w = (char*)d_ws;
    auto alloc = [&](size_t bytes) {
        char* p = w;
        w += (bytes + 255) & ~(size_t)255;
        return p;
    };
    float* posPart = (float*)alloc((size_t)NL * ND * 4);
    float* hs      = (float*)alloc((size_t)NB * ND * 4);
    float* betav   = (float*)alloc((size_t)ROWS * NK * 4);
    __hip_bfloat16* XbG     = (__hip_bfloat16*)alloc((size_t)ROWS * ND * 2);
    __hip_bfloat16* w1h_t   = (__hip_bfloat16*)alloc((size_t)ND * ND * 2);
    __hip_bfloat16* attw2_t = (__hip_bfloat16*)alloc((size_t)ND * ND * 2);
    __hip_bfloat16* glu_t   = (__hip_bfloat16*)alloc((size_t)512 * ND * 2);
    __hip_bfloat16* selb    = (__hip_bfloat16*)alloc((size_t)MROWS * ND * 2);
    __hip_bfloat16* bnv     = (__hip_bfloat16*)alloc((size_t)NPAD2 * ND * 2);

    k_prep<<<G_TOT, 256, 0, stream>>>(hidden, mask, pos_emb, w1, att_w2, glu1_w, emb,
                                      hs, posPart, XbG, w1h_t, attw2_t, glu_t, bnv, loss_out);
    k_mega<<<ROWS / MR, 256, 0, stream>>>(XbG, w1h_t, attw2_t, glu_t, hs, att_w1,
                                          att_v, posPart, glu1_b, w2, mask, betav);
    k_loss<<<NB, 64, 0, stream>>>(betav, mask, loss_out);
    k_select<<<NB / 2, 256, 0, stream>>>(betav, hidden, selb);
    k_gemm<<<dim3(NPAD2 / GEMM_NSPAN, MROWS / 128), 256, 0, stream>>>(selb, bnv, scores, max_out);
}

// Round 4
// 420.823 us; speedup vs baseline: 1.3772x; 1.0275x over previous
//
#include <hip/hip_runtime.h>
#include <hip/hip_bf16.h>
#include <math.h>

// Problem constants
constexpr int NB = 256;      // batch
constexpr int NL = 50;       // seq len
constexpr int ND = 128;      // dim
constexpr int NK = 4;        // interests
constexpr int NVm1 = 49999;  // V-1
constexpr int NPAD2 = 50176; // N padded to 392*128
constexpr int ROWS = NB * NL;   // 12800
constexpr int MROWS = NB * NK;  // 1024 (rows of select, b-major: row = b*4+k)
constexpr int GEMM_NSPAN = 512; // n cols per block in big GEMM (8 chunks of 64)
constexpr int MR = 64;          // rows per mega block

// prep kernel block ranges
constexpr int G_BN  = NPAD2 / 8;  // 6272 bnorm (8 rows/blk, float4 per thread)
constexpr int G_HW  = NB / 2;     // 128 hsW1 = (masked-mean hidden) @ att_w1 (2 b/blk)
constexpr int G_PP  = NL / 2;     // 25 posPart (2 rows/blk)
constexpr int G_XB  = ROWS * ND / 2048; // 800 Xb cast
constexpr int G_W1T = ND * ND / 256;    // 64
constexpr int G_AWT = ND * ND / 256;    // 64
constexpr int G_GLT = ND * 512 / 256;   // 256
constexpr int G_TOT = G_BN + G_HW + G_PP + G_XB + G_W1T + G_AWT + G_GLT;

typedef __bf16 bf16x8 __attribute__((ext_vector_type(8)));
typedef float f32x4 __attribute__((ext_vector_type(4)));
typedef f32x4 f32x4u __attribute__((aligned(4))); // align-4 vector (scores rows are not 16B-aligned)

__device__ __forceinline__ float sigm_fast(float x) { return 1.0f / (1.0f + __expf(-x)); }
__device__ __forceinline__ float sigm_prec(float x) { return 1.0f / (1.0f + expf(-x)); }
__device__ __forceinline__ float fast_tanh(float x) {
    float xc = fminf(fmaxf(x, -15.f), 15.f);
    float e = __expf(2.f * xc);
    return (e - 1.f) / (e + 1.f);
}

__device__ __forceinline__ void gld_lds16(const void* g, void* l) {
    __builtin_amdgcn_global_load_lds(
        (const __attribute__((address_space(1))) void*)g,
        (__attribute__((address_space(3))) void*)l, 16, 0, 0);
}

// ---------------- K0: prep — bnorm, hsW1, posPart, Xb cast, weight transposes ----------------
__global__ __launch_bounds__(256) void k_prep(
    const float* __restrict__ hidden, const int* __restrict__ mask,
    const float* __restrict__ pos_emb, const float* __restrict__ w1,
    const float* __restrict__ att_w1, const float* __restrict__ att_w2,
    const float* __restrict__ glu1_w, const float* __restrict__ emb,
    float* __restrict__ hsW1, float* __restrict__ posPart,
    __hip_bfloat16* __restrict__ XbG, __hip_bfloat16* __restrict__ w1h_t,
    __hip_bfloat16* __restrict__ attw2_t, __hip_bfloat16* __restrict__ glu_t,
    __hip_bfloat16* __restrict__ bnv, float* __restrict__ loss_out) {
    __shared__ float sPP[2 * ND];
    int blk = blockIdx.x, tid = threadIdx.x;
    if (blk < G_BN) {
        // bnorm: rows emb[1:] L2-normalized -> bf16; padded rows -> 0.
        // 8 rows/block, 32 threads/row, float4 per thread.
        int v = blk * 8 + (tid >> 5);
        int j = (tid & 31) << 2;
        float4 x = make_float4(0.f, 0.f, 0.f, 0.f);
        if (v < NVm1) x = *(const float4*)&emb[((size_t)v + 1) * ND + j];
        float ss = x.x * x.x + x.y * x.y + x.z * x.z + x.w * x.w;
#pragma unroll
        for (int off = 16; off >= 1; off >>= 1) ss += __shfl_xor(ss, off);
        float rn = 1.f / fmaxf(sqrtf(ss), 1e-12f);
        union { ushort4 u4; __hip_bfloat16 h[4]; } o;
        o.h[0] = __float2bfloat16(x.x * rn);
        o.h[1] = __float2bfloat16(x.y * rn);
        o.h[2] = __float2bfloat16(x.z * rn);
        o.h[3] = __float2bfloat16(x.w * rn);
        *(ushort4*)&bnv[(size_t)v * ND + j] = o.u4;
    } else if (blk < G_BN + G_HW) {
        // hsW1[b][d] = (masked-mean of hidden[b]) @ att_w1 — precomputed so k_mega
        // doesn't burn ~100K scalar global loads per block on this dot.
        int half = tid >> 7, d = tid & 127;
        int b = (blk - G_BN) * 2 + half;
        float acc = 0.f, msum = 0.f;
        for (int l = 0; l < NL; ++l) {
            float mv = (float)mask[b * NL + l];
            acc += hidden[((size_t)b * NL + l) * ND + d] * mv;
            msum += mv;
        }
        sPP[half * ND + d] = acc / msum;
        __syncthreads();
        float o = 0.f;
#pragma unroll 8
        for (int j = 0; j < ND; ++j) o += sPP[half * ND + j] * att_w1[j * ND + d];
        hsW1[b * ND + d] = o;
        if (blk == G_BN && tid == 0) loss_out[0] = 0.f;
    } else if (blk < G_BN + G_HW + G_PP) {
        int rel = blk - (G_BN + G_HW);
        int rl = tid >> 7, d = tid & 127;
        int r = rel * 2 + rl;
        sPP[rl * ND + d] = pos_emb[r * ND + d];
        __syncthreads();
        float acc = 0.f;
#pragma unroll 8
        for (int j = 0; j < ND; ++j) acc += sPP[rl * ND + j] * w1[j * ND + d]; // w1 upper half
        posPart[r * ND + d] = acc;
    } else if (blk < G_BN + G_HW + G_PP + G_XB) {
        int rel = blk - (G_BN + G_HW + G_PP);
        size_t base = (size_t)rel * 2048 + (size_t)tid * 8;
        float4 f0 = *(const float4*)&hidden[base];
        float4 f1 = *(const float4*)&hidden[base + 4];
        union { bf16x8 v; __hip_bfloat16 h[8]; } u;
        u.h[0] = __float2bfloat16(f0.x); u.h[1] = __float2bfloat16(f0.y);
        u.h[2] = __float2bfloat16(f0.z); u.h[3] = __float2bfloat16(f0.w);
        u.h[4] = __float2bfloat16(f1.x); u.h[5] = __float2bfloat16(f1.y);
        u.h[6] = __float2bfloat16(f1.z); u.h[7] = __float2bfloat16(f1.w);
        *(bf16x8*)&XbG[base] = u.v;
    } else if (blk < G_BN + G_HW + G_PP + G_XB + G_W1T) {
        int i = (blk - (G_BN + G_HW + G_PP + G_XB)) * 256 + tid;
        int d = i >> 7, j = i & 127;
        w1h_t[d * ND + j] = __float2bfloat16(w1[(ND + j) * ND + d]); // lower (hidden) half
    } else if (blk < G_BN + G_HW + G_PP + G_XB + G_W1T + G_AWT) {
        int i = (blk - (G_BN + G_HW + G_PP + G_XB + G_W1T)) * 256 + tid;
        int d = i >> 7, j = i & 127;
        attw2_t[d * ND + j] = __float2bfloat16(att_w2[j * ND + d]);
    } else {
        int i = (blk - (G_BN + G_HW + G_PP + G_XB + G_W1T + G_AWT)) * 256 + tid;
        int c = i >> 7, j = i & 127;
        glu_t[c * ND + j] = __float2bfloat16(glu1_w[j * 512 + c]);
    }
}

// ---------------- K1: mega — GEMM1(att,nh via MFMA) + alpha + GEMM2(glu) + beta ----------------
__global__ __launch_bounds__(256) void k_mega(
    const __hip_bfloat16* __restrict__ XbG, const __hip_bfloat16* __restrict__ w1h_t,
    const __hip_bfloat16* __restrict__ attw2_t, const __hip_bfloat16* __restrict__ glu_t,
    const float* __restrict__ hsW1, const float* __restrict__ att_v,
    const float* __restrict__ posPart, const float* __restrict__ glu1_b,
    const float* __restrict__ w2, const int* __restrict__ mask,
    float* __restrict__ beta_out) {
    __shared__ __hip_bfloat16 XbS[MR * ND];   // 16 KB swizzled
    __shared__ __hip_bfloat16 WS[ND * ND];    // 32 KB swizzled
    __shared__ __attribute__((aligned(16))) __hip_bfloat16 NHS[MR * 136]; // padded (+8)
    __shared__ float alphaS[MR * NK];
    __shared__ float hsW1S[3 * ND];
    int row0 = blockIdx.x * MR;
    int tid = threadIdx.x;
    int wave = tid >> 6, lane = tid & 63, l16 = lane & 15, quad = lane >> 4;
    int b0 = row0 / NL;

#pragma unroll
    for (int it = 0; it < 4; ++it) {
        int id = it * 256 + tid;
        int row = id >> 4, c = id & 15, gc = c ^ (row & 7);
        gld_lds16((const char*)XbG + ((size_t)(row0 + row) * 16 + gc) * 16,
                  (char*)XbS + (size_t)(it * 256 + wave * 64) * 16);
    }
#pragma unroll
    for (int it = 0; it < 8; ++it) {
        int id = it * 256 + tid;
        int row = id >> 4, c = id & 15, gc = c ^ (row & 7);
        gld_lds16((const char*)attw2_t + ((size_t)row * 16 + gc) * 16,
                  (char*)WS + (size_t)(it * 256 + wave * 64) * 16);
    }
    for (int i = tid; i < 3 * ND; i += 256) {
        int b = b0 + (i >> 7);
        hsW1S[i] = (b < NB) ? hsW1[b * ND + (i & 127)] : 0.f;
    }
    __syncthreads();

    const bf16x8* Xv = (const bf16x8*)XbS;
    const bf16x8* Wv = (const bf16x8*)WS;
    const bf16x8* Nv = (const bf16x8*)NHS; // row stride 17 (136 bf16)
    int arow = wave * 16 + l16;

    f32x4 acc8[8];
    // ---- GEMM1-att ----
#pragma unroll
    for (int ni = 0; ni < 8; ++ni) acc8[ni] = (f32x4){0.f, 0.f, 0.f, 0.f};
#pragma unroll
    for (int kk = 0; kk < 4; ++kk) {
        int ko = kk * 4 + quad;
        bf16x8 af = Xv[arow * 16 + (ko ^ (arow & 7))];
#pragma unroll
        for (int ni = 0; ni < 8; ++ni) {
            int n = ni * 16 + l16;
            bf16x8 bf = Wv[n * 16 + (ko ^ (n & 7))];
            acc8[ni] = __builtin_amdgcn_mfma_f32_16x16x32_bf16(af, bf, acc8[ni], 0, 0, 0);
        }
    }
#pragma unroll
    for (int r = 0; r < 4; ++r) {
        int lrow = wave * 16 + quad * 4 + r;
        int grow = row0 + lrow;
        int bb = grow / NL - b0;
        float a0 = 0.f, a1 = 0.f, a2 = 0.f, a3 = 0.f;
#pragma unroll
        for (int ni = 0; ni < 8; ++ni) {
            int col = ni * 16 + l16;
            float atv = fast_tanh(hsW1S[bb * ND + col] + acc8[ni][r]);
            float4 av = *(const float4*)&att_v[col * 4];
            a0 += atv * av.x; a1 += atv * av.y; a2 += atv * av.z; a3 += atv * av.w;
        }
#pragma unroll
        for (int off = 1; off < 16; off <<= 1) {
            a0 += __shfl_xor(a0, off); a1 += __shfl_xor(a1, off);
            a2 += __shfl_xor(a2, off); a3 += __shfl_xor(a3, off);
        }
        if (l16 == 0) {
            alphaS[lrow * 4 + 0] = sigm_fast(a0);
            alphaS[lrow * 4 + 1] = sigm_fast(a1);
            alphaS[lrow * 4 + 2] = sigm_fast(a2);
            alphaS[lrow * 4 + 3] = sigm_fast(a3);
        }
    }
    __syncthreads(); // WS reads done
#pragma unroll
    for (int it = 0; it < 8; ++it) {
        int id = it * 256 + tid;
        int row = id >> 4, c = id & 15, gc = c ^ (row & 7);
        gld_lds16((const char*)w1h_t + ((size_t)row * 16 + gc) * 16,
                  (char*)WS + (size_t)(it * 256 + wave * 64) * 16);
    }
    __syncthreads();
    // ---- GEMM1-nh ----
#pragma unroll
    for (int ni = 0; ni < 8; ++ni) acc8[ni] = (f32x4){0.f, 0.f, 0.f, 0.f};
#pragma unroll
    for (int kk = 0; kk < 4; ++kk) {
        int ko = kk * 4 + quad;
        bf16x8 af = Xv[arow * 16 + (ko ^ (arow & 7))];
#pragma unroll
        for (int ni = 0; ni < 8; ++ni) {
            int n = ni * 16 + l16;
            bf16x8 bf = Wv[n * 16 + (ko ^ (n & 7))];
            acc8[ni] = __builtin_amdgcn_mfma_f32_16x16x32_bf16(af, bf, acc8[ni], 0, 0, 0);
        }
    }
#pragma unroll
    for (int r = 0; r < 4; ++r) {
        int lrow = wave * 16 + quad * 4 + r;
        int grow = row0 + lrow;
        int l = grow % NL;
#pragma unroll
        for (int ni = 0; ni < 8; ++ni) {
            int col = ni * 16 + l16;
            float nhv = fast_tanh(posPart[l * ND + col] + acc8[ni][r]);
            NHS[lrow * 136 + col] = __float2bfloat16(nhv);
        }
    }
    __syncthreads(); // NHS complete, WS free
    // ---- GEMM2: 4 chunks of 128 cols; chunk ch == k-segment ch ----
    for (int ch = 0; ch < 4; ++ch) {
#pragma unroll
        for (int it = 0; it < 8; ++it) {
            int id = it * 256 + tid;
            int row = id >> 4, c = id & 15, gc = c ^ (row & 7);
            gld_lds16((const char*)glu_t + ((size_t)(ch * ND + row) * 16 + gc) * 16,
                      (char*)WS + (size_t)(it * 256 + wave * 64) * 16);
        }
        __syncthreads();
#pragma unroll
        for (int ni = 0; ni < 8; ++ni) acc8[ni] = (f32x4){0.f, 0.f, 0.f, 0.f};
#pragma unroll
        for (int kk = 0; kk < 4; ++kk) {
            int ko = kk * 4 + quad;
            bf16x8 af = Nv[arow * 17 + ko]; // padded, no swizzle
#pragma unroll
            for (int ni = 0; ni < 8; ++ni) {
                int n = ni * 16 + l16;
                bf16x8 bf = Wv[n * 16 + (ko ^ (n & 7))];
                acc8[ni] = __builtin_amdgcn_mfma_f32_16x16x32_bf16(af, bf, acc8[ni], 0, 0, 0);
            }
        }
#pragma unroll
        for (int r = 0; r < 4; ++r) {
            float s = 0.f;
#pragma unroll
            for (int ni = 0; ni < 8; ++ni) {
                int col = ni * 16 + l16;
                s += sigm_fast(acc8[ni][r] + glu1_b[ch * ND + col]) * w2[col * 4 + ch];
            }
#pragma unroll
            for (int off = 1; off < 16; off <<= 1) s += __shfl_xor(s, off);
            if (l16 == 0) {
                int lrow = wave * 16 + quad * 4 + r;
                int grow = row0 + lrow;
                float a = alphaS[lrow * 4 + ch];
                beta_out[(size_t)grow * 4 + ch] = s * (0.5f + a) * (float)mask[grow];
            }
        }
        __syncthreads();
    }
}

// ---------------- K2: loss (lens inline, atomic accumulate) ----------------
__global__ void k_loss(const float* __restrict__ beta, const int* __restrict__ mask,
                       float* __restrict__ loss_out) {
    int b = blockIdx.x;
    int t = threadIdx.x; // 64
    float mv = (t < NL) ? (float)mask[b * NL + t] : 0.f;
    float msum = mv;
    for (int off = 32; off >= 1; off >>= 1) msum += __shfl_xor(msum, off);
    float lens = msum - 5.0f; // LENGTH=5
    float bk[NK] = {0.f, 0.f, 0.f, 0.f};
    if (t < NL) {
#pragma unroll
        for (int k = 0; k < NK; ++k) bk[k] = beta[((size_t)b * NL + t) * NK + k];
    }
    float nb[NK];
#pragma unroll
    for (int k = 0; k < NK; ++k) {
        float v = bk[k] * bk[k];
        for (int off = 32; off >= 1; off >>= 1) v += __shfl_xor(v, off);
        nb[k] = bk[k] / fmaxf(sqrtf(v), 1e-12f);
    }
    float sim = 0.f;
#pragma unroll
    for (int i = 0; i < NK; ++i) {
#pragma unroll
        for (int j = 0; j < NK; ++j) {
            if (j > i) {
                float p = nb[i] * nb[j];
                for (int off = 32; off >= 1; off >>= 1) p += __shfl_xor(p, off);
                sim += fabsf(p);
            }
        }
    }
    sim *= (2.0f / (NK * (NK - 1)));
    if (t == 0) atomicAdd(loss_out, sigm_prec(sim * lens) * 0.01f); // BETA
}

// ---------------- K3: select -> bf16 (2 b per block) ----------------
__global__ __launch_bounds__(256) void k_select(
    const float* __restrict__ beta, const float* __restrict__ hidden,
    __hip_bfloat16* __restrict__ selb) {
    int b = blockIdx.x * 2 + (threadIdx.x >> 7);
    int d = threadIdx.x & 127;
    float a0 = 0.f, a1 = 0.f, a2 = 0.f, a3 = 0.f;
    for (int l = 0; l < NL; ++l) {
        float h = hidden[((size_t)b * NL + l) * ND + d];
        float4 bv = *(const float4*)&beta[((size_t)b * NL + l) * NK];
        a0 = fmaf(bv.x, h, a0);
        a1 = fmaf(bv.y, h, a1);
        a2 = fmaf(bv.z, h, a2);
        a3 = fmaf(bv.w, h, a3);
    }
    selb[((size_t)b * NK + 0) * ND + d] = __float2bfloat16(a0);
    selb[((size_t)b * NK + 1) * ND + d] = __float2bfloat16(a1);
    selb[((size_t)b * NK + 2) * ND + d] = __float2bfloat16(a2);
    selb[((size_t)b * NK + 3) * ND + d] = __float2bfloat16(a3);
}

// ---------------- K4: big GEMM  C[1024,NPAD2] = selb @ bnv^T ----------------
// Store-bound (256 MB fp32 out). Round-2 post-mortem: per-chunk stores dirty 256 B
// per row scattered across 256 MB -> DRAM page thrash (~2.2 TB/s effective). Fix:
// block = 64 m x 512 n, SWAPPED mfma(bn, selb) -> D[n][m] so each lane's 4 regs are
// 4 consecutive n of ONE row (m = l16 within wave's 16-row group). All 32 n-tiles
// accumulate in 128 VGPRs; the K-loop has ZERO stores; epilogue writes each row's
// full 2 KB as 32 sequential dwordx4 -> fill-like sequential streams. maxs via
// 2x shfl_xor over the 4-lane k-group (rows b*4+k are consecutive m), same layout.
// bnv (12.8 MB) is LLC-resident, so the x16 y-replication of B reads is cheap.
// Sync: plain double-buffer + __syncthreads() (round-3's raw-barrier/counted-vmcnt
// variant is suspected of killing the container; the per-chunk drain of 4 LLC-hit
// glds is ~1-2 us total — negligible vs the store-locality win under test).
__global__ __launch_bounds__(256) void k_gemm(
    const __hip_bfloat16* __restrict__ selb, const __hip_bfloat16* __restrict__ bn,
    float* __restrict__ scores, float* __restrict__ maxs) {
    __shared__ __attribute__((aligned(16))) __hip_bfloat16 As[64 * 128];     // 16 KB
    __shared__ __attribute__((aligned(16))) __hip_bfloat16 Bs[2][64 * 128];  // 2x16 KB
    int bm0 = blockIdx.y * 64;
    int nbase = blockIdx.x * GEMM_NSPAN;
    int tid = threadIdx.x;
    int wave = tid >> 6, lane = tid & 63;
    int l16 = lane & 15, quad = lane >> 4;
    int m_loc = wave * 16; // wave owns 16 m-rows x all 512 n
    bool full = (nbase + GEMM_NSPAN) <= NVm1;
    const size_t SC_K = (size_t)NB * NVm1;

    // prologue: stage As (4 glds) + Bs[0] (4 glds)
#pragma unroll
    for (int it = 0; it < 4; ++it) {
        int id = it * 256 + tid;
        int row = id >> 4, c = id & 15, gc = c ^ (row & 7);
        gld_lds16((const char*)selb + ((size_t)(bm0 + row) * 16 + gc) * 16,
                  (char*)As + (size_t)(it * 256 + wave * 64) * 16);
    }
#pragma unroll
    for (int it = 0; it < 4; ++it) {
        int id = it * 256 + tid;
        int row = id >> 4, c = id & 15, gc = c ^ (row & 7);
        gld_lds16((const char*)bn + ((size_t)(nbase + row) * 16 + gc) * 16,
                  (char*)Bs[0] + (size_t)(it * 256 + wave * 64) * 16);
    }
    __syncthreads();

    const bf16x8* Av = (const bf16x8*)As;
    bf16x8 sf[4];     // selb fragments (B-operand), constant across chunks
#pragma unroll
    for (int kk = 0; kk < 4; ++kk) {
        int row = m_loc + l16, ko = kk * 4 + quad;
        sf[kk] = Av[row * 16 + (ko ^ (row & 7))];
    }

    f32x4 acc[32];    // 128 VGPR accumulator: acc[flat], flat = ch*4+ni, n-tile = flat
#pragma unroll
    for (int i = 0; i < 32; ++i) acc[i] = (f32x4){0.f, 0.f, 0.f, 0.f};

#pragma unroll
    for (int ch = 0; ch < 8; ++ch) {
        // prefetch next chunk into the other buffer (issued before compute so the
        // LLC-hit latency overlaps the 16 MFMAs; drained by the __syncthreads below)
        if (ch < 7) {
            int bn0 = nbase + (ch + 1) * 64;
#pragma unroll
            for (int it = 0; it < 4; ++it) {
                int id = it * 256 + tid;
                int row = id >> 4, c = id & 15, gc = c ^ (row & 7);
                gld_lds16((const char*)bn + ((size_t)(bn0 + row) * 16 + gc) * 16,
                          (char*)Bs[(ch + 1) & 1] + (size_t)(it * 256 + wave * 64) * 16);
            }
        }
        const bf16x8* Bv = (const bf16x8*)Bs[ch & 1];
#pragma unroll
        for (int kk = 0; kk < 4; ++kk) {
            int ko = kk * 4 + quad;
            bf16x8 af[4];
#pragma unroll
            for (int ni = 0; ni < 4; ++ni) {
                int row = ni * 16 + l16;
                af[ni] = Bv[row * 16 + (ko ^ (row & 7))];
            }
#pragma unroll
            for (int ni = 0; ni < 4; ++ni)
                acc[ch * 4 + ni] = __builtin_amdgcn_mfma_f32_16x16x32_bf16(
                    af[ni], sf[kk], acc[ch * 4 + ni], 0, 0, 0);
        }
        __syncthreads(); // prefetch complete + all reads of Bs[ch&1] done
    }

    // epilogue: lane owns row m = bm0 + m_loc + l16 -> k = m&3 = l16&3, b = m>>2.
    // acc[flat][r] = C[n = nbase + flat*16 + quad*4 + r][m]. 32 sequential align-4
    // dwordx4 stores cover the row's full 2 KB n-span.
    int m = bm0 + m_loc + l16;
    float* srow = scores + (size_t)(l16 & 3) * SC_K + (size_t)(m >> 2) * NVm1;
    float* mrow = maxs + (size_t)(m >> 2) * NVm1;
    if (full) {
#pragma unroll
        for (int ni = 0; ni < 32; ++ni) {
            int n0 = nbase + ni * 16 + quad * 4;
            f32x4 v = acc[ni];
            *(f32x4u*)&srow[n0] = v;
            f32x4 w;
#pragma unroll
            for (int c = 0; c < 4; ++c) {
                float t = fmaxf(v[c], __shfl_xor(v[c], 1));
                w[c] = fmaxf(t, __shfl_xor(t, 2));
            }
            if ((l16 & 3) == 0) *(f32x4u*)&mrow[n0] = w;
        }
    } else {
#pragma unroll
        for (int ni = 0; ni < 32; ++ni) {
            int n0 = nbase + ni * 16 + quad * 4;
            f32x4 v = acc[ni];
            f32x4 w;
#pragma unroll
            for (int c = 0; c < 4; ++c) {
                float t = fmaxf(v[c], __shfl_xor(v[c], 1));
                w[c] = fmaxf(t, __shfl_xor(t, 2));
            }
#pragma unroll
            for (int c = 0; c < 4; ++c) {
                if (n0 + c < NVm1) {
                    srow[n0 + c] = v[c];
                    if ((l16 & 3) == 0) mrow[n0 + c] = w[c];
                }
            }
        }
    }
}

extern "C" void kernel_launch(void* const* d_in, const int* in_sizes, int n_in,
                              void* d_out, int out_size, void* d_ws, size_t ws_size,
                              hipStream_t stream) {
    const float* hidden  = (const float*)d_in[0];
    const int*   mask    = (const int*)d_in[1];
    const float* pos_emb = (const float*)d_in[2];
    const float* w1      = (const float*)d_in[3];
    const float* w2      = (const float*)d_in[4];
    const float* glu1_w  = (const float*)d_in[5];
    const float* glu1_b  = (const float*)d_in[6];
    const float* att_w1  = (const float*)d_in[7];
    const float* att_w2  = (const float*)d_in[8];
    const float* att_v   = (const float*)d_in[9];
    const float* emb     = (const float*)d_in[10];

    float* out      = (float*)d_out;
    float* max_out  = out;                                   // [B, NVm1]
    float* loss_out = out + (size_t)NB * NVm1;               // scalar
    float* scores   = out + (size_t)NB * NVm1 + 1;           // [K, B, NVm1]

    char* w = (char*)d_ws;
    auto alloc = [&](size_t bytes) {
        char* p = w;
        w += (bytes + 255) & ~(size_t)255;
        return p;
    };
    float* posPart = (float*)alloc((size_t)NL * ND * 4);
    float* hsW1    = (float*)alloc((size_t)NB * ND * 4);
    float* betav   = (float*)alloc((size_t)ROWS * NK * 4);
    __hip_bfloat16* XbG     = (__hip_bfloat16*)alloc((size_t)ROWS * ND * 2);
    __hip_bfloat16* w1h_t   = (__hip_bfloat16*)alloc((size_t)ND * ND * 2);
    __hip_bfloat16* attw2_t = (__hip_bfloat16*)alloc((size_t)ND * ND * 2);
    __hip_bfloat16* glu_t   = (__hip_bfloat16*)alloc((size_t)512 * ND * 2);
    __hip_bfloat16* selb    = (__hip_bfloat16*)alloc((size_t)MROWS * ND * 2);
    __hip_bfloat16* bnv     = (__hip_bfloat16*)alloc((size_t)NPAD2 * ND * 2);

    k_prep<<<G_TOT, 256, 0, stream>>>(hidden, mask, pos_emb, w1, att_w1, att_w2, glu1_w,
                                      emb, hsW1, posPart, XbG, w1h_t, attw2_t, glu_t,
                                      bnv, loss_out);
    k_mega<<<ROWS / MR, 256, 0, stream>>>(XbG, w1h_t, attw2_t, glu_t, hsW1,
                                          att_v, posPart, glu1_b, w2, mask, betav);
    k_loss<<<NB, 64, 0, stream>>>(betav, mask, loss_out);
    k_select<<<NB / 2, 256, 0, stream>>>(betav, hidden, selb);
    k_gemm<<<dim3(NPAD2 / GEMM_NSPAN, MROWS / 64), 256, 0, stream>>>(selb, bnv, scores, max_out);
}